// Round 3
// baseline (288.188 us; speedup 1.0000x reference)
//
#include <hip/hip_runtime.h>
#include <hip/hip_bf16.h>

#define NTOK 4096   // B*S
#define HD   1024   // hidden
#define DD   2048   // expert hidden
#define NE   8      // experts
#define SLOTS (2*NTOK)
#define SLOTS_PAD (SLOTS + 128)

typedef unsigned short u16;
typedef unsigned int   u32;
typedef __attribute__((ext_vector_type(8))) __bf16 bf16x8;
typedef __attribute__((ext_vector_type(4))) float  f32x4;

__device__ __forceinline__ float bf2f(u16 u) {
    u32 v = ((u32)u) << 16;
    return __uint_as_float(v);
}
__device__ __forceinline__ u16 f2bf(float f) {
    __hip_bfloat16 h = __float2bfloat16(f);   // RTN
    return *reinterpret_cast<u16*>(&h);
}

__device__ __forceinline__ void gload_lds16(const void* g, void* l) {
    __builtin_amdgcn_global_load_lds(
        (__attribute__((address_space(1))) void*)g,
        (__attribute__((address_space(3))) void*)l,
        16, 0, 0);
}

// ---------------- convert + transpose weights: src [e][R][C] f32 -> dst [e][C][R] bf16
template<int R, int C>
__global__ __launch_bounds__(256) void cvtT_k(const float* __restrict__ src,
                                              u16* __restrict__ dst) {
    __shared__ u16 tile[32][33];
    int e  = blockIdx.z;
    int c0 = blockIdx.x * 32, r0 = blockIdx.y * 32;
    int tx = threadIdx.x & 31, ty = threadIdx.x >> 5;   // 32 x 8
    const float* s = src + (size_t)e * R * C;
    u16* d = dst + (size_t)e * C * R;
#pragma unroll
    for (int j = 0; j < 4; ++j) {
        int r = ty + j * 8;
        tile[r][tx] = f2bf(s[(size_t)(r0 + r) * C + c0 + tx]);
    }
    __syncthreads();
#pragma unroll
    for (int j = 0; j < 4; ++j) {
        int cc = ty + j * 8;
        d[(size_t)(c0 + cc) * R + r0 + tx] = tile[tx][cc];
    }
}

// ---------------- router (fused x->bf16 convert): 1 wave per token ----------------
__global__ __launch_bounds__(256) void router_k(
        const float* __restrict__ x, const float* __restrict__ gw,
        u16* __restrict__ xb,
        int* __restrict__ counts, float* __restrict__ sum_probs,
        int* __restrict__ tk_idx, float* __restrict__ tk_w) {
    __shared__ int   bcnt[NE];
    __shared__ float bprob[NE];
    int tid = threadIdx.x;
    if (tid < NE) { bcnt[tid] = 0; bprob[tid] = 0.f; }
    __syncthreads();

    int gtid = blockIdx.x * 256 + tid;
    int t    = gtid >> 6;
    int lane = gtid & 63;

    float acc[NE] = {0.f,0.f,0.f,0.f,0.f,0.f,0.f,0.f};
    const float* xr = x + (size_t)t * HD;
    u16* xbr = xb + (size_t)t * HD;
#pragma unroll
    for (int i = 0; i < HD / 64; ++i) {
        int h = lane + i * 64;
        float xv = xr[h];
        xbr[h] = f2bf(xv);   // fused bf16 convert
        const float4* g = reinterpret_cast<const float4*>(gw + (size_t)h * NE);
        float4 g0 = g[0], g1 = g[1];
        acc[0] = fmaf(xv, g0.x, acc[0]); acc[1] = fmaf(xv, g0.y, acc[1]);
        acc[2] = fmaf(xv, g0.z, acc[2]); acc[3] = fmaf(xv, g0.w, acc[3]);
        acc[4] = fmaf(xv, g1.x, acc[4]); acc[5] = fmaf(xv, g1.y, acc[5]);
        acc[6] = fmaf(xv, g1.z, acc[6]); acc[7] = fmaf(xv, g1.w, acc[7]);
    }
#pragma unroll
    for (int off = 32; off >= 1; off >>= 1) {
#pragma unroll
        for (int e = 0; e < NE; ++e) acc[e] += __shfl_xor(acc[e], off);
    }
    float m = acc[0];
#pragma unroll
    for (int e = 1; e < NE; ++e) m = fmaxf(m, acc[e]);
    float p[NE]; float s = 0.f;
#pragma unroll
    for (int e = 0; e < NE; ++e) { p[e] = expf(acc[e] - m); s += p[e]; }
    float inv = 1.f / s;

    int i1 = 0; float v1 = p[0];
#pragma unroll
    for (int e = 1; e < NE; ++e) if (p[e] > v1) { v1 = p[e]; i1 = e; }
    int i2 = -1; float v2 = -1.f;
#pragma unroll
    for (int e = 0; e < NE; ++e) if (e != i1 && p[e] > v2) { v2 = p[e]; i2 = e; }
    float wsum = v1 + v2;

    if (lane < NE) atomicAdd(&bprob[lane], p[lane] * inv);
    if (lane == 0) {
        atomicAdd(&bcnt[i1], 1);
        atomicAdd(&bcnt[i2], 1);
        tk_idx[2 * t]     = i1;  tk_idx[2 * t + 1] = i2;
        tk_w[2 * t]       = v1 / wsum;
        tk_w[2 * t + 1]   = v2 / wsum;
    }
    __syncthreads();
    if (tid < NE) {
        if (bcnt[tid]) atomicAdd(&counts[tid], bcnt[tid]);
        atomicAdd(&sum_probs[tid], bprob[tid]);
    }
}

// ---------------- exclusive scan over 8 experts ----------------
__global__ void scan_k(const int* __restrict__ counts, int* __restrict__ offsets) {
    if (threadIdx.x == 0) {
        int o = 0;
        for (int e = 0; e < NE; ++e) { offsets[e] = o; o += counts[e]; }
    }
}

// ---------------- scatter tokens into expert-grouped slots ----------------
__global__ __launch_bounds__(256) void scatter_k(
        const int* __restrict__ tk_idx, const int* __restrict__ offsets,
        int* __restrict__ cursor, int* __restrict__ slot_tok,
        int* __restrict__ inv_slot) {
    int t = blockIdx.x * 256 + threadIdx.x;
    if (t >= NTOK) return;
#pragma unroll
    for (int k = 0; k < 2; ++k) {
        int e = tk_idx[2 * t + k];
        int pos = atomicAdd(&cursor[e], 1);
        int s = offsets[e] + pos;
        slot_tok[s] = t;
        inv_slot[2 * t + k] = s;
    }
}

// ---------------- grouped MFMA GEMM, 2-phase double-buffered (T3-minimum) ----------
// C[m][n] = sum_k A[m][k] * Bt[n][k]   per expert, 128x128 tile, BK=32
// 4 waves 2x2, each wave 64x64 via 4x4 frags of v_mfma_f32_16x16x32_bf16
template<int KD, int ND, bool GATHER, bool GELU>
__global__ __launch_bounds__(256) void gemm_mfma_k(
        const u16* __restrict__ A,      // GATHER: xb [NTOK][KD]; else hbuf [SLOTS_PAD][KD]
        const u16* __restrict__ Bt,     // [NE][ND][KD]
        const float* __restrict__ bias, // GELU: b1 [NE][ND]
        const int* __restrict__ counts, const int* __restrict__ offsets,
        const int* __restrict__ slot_tok,
        u16* __restrict__ outb) {       // [SLOTS_PAD][ND]
    int e   = blockIdx.z;
    int cnt = counts[e];
    int m0  = blockIdx.y * 128;
    if (m0 >= cnt) return;
    int n0   = blockIdx.x * 128;
    int base = offsets[e];

    __shared__ u16 Asm[2][128 * 32];   // 8 KiB per buffer
    __shared__ u16 Bsm[2][128 * 32];
    __shared__ int ids[128];

    int tid  = threadIdx.x;
    int lane = tid & 63;
    int w    = tid >> 6;

    if constexpr (GATHER) {
        if (tid < 128) ids[tid] = (m0 + tid < cnt) ? slot_tok[base + m0 + tid] : 0;
    }
    __syncthreads();

    const u16* Bte = Bt + (size_t)e * ND * KD;
    int srow = w * 16 + (lane >> 2);      // staged row within half-tile
    int skk  = (lane & 3) * 8;            // staged k offset (elems)

    size_t arow0, arow1;
    if constexpr (GATHER) {
        arow0 = (size_t)ids[srow]      * KD;
        arow1 = (size_t)ids[srow + 64] * KD;
    } else {
        arow0 = (size_t)(base + m0 + srow)      * KD;
        arow1 = (size_t)(base + m0 + srow + 64) * KD;
    }
    size_t brow0 = (size_t)(n0 + srow)      * KD;
    size_t brow1 = (size_t)(n0 + srow + 64) * KD;

    int wr = w >> 1, wc = w & 1;
    int lrow = lane & 15, lk8 = (lane >> 4) * 8;

    f32x4 acc[4][4];
#pragma unroll
    for (int m = 0; m < 4; ++m)
#pragma unroll
        for (int n = 0; n < 4; ++n) acc[m][n] = {0.f, 0.f, 0.f, 0.f};

    auto stage = [&](int buf, int k0) {
        char* as = (char*)Asm[buf];
        char* bs = (char*)Bsm[buf];
        gload_lds16(A + arow0 + k0 + skk,   as + w * 1024);
        gload_lds16(A + arow1 + k0 + skk,   as + 4096 + w * 1024);
        gload_lds16(Bte + brow0 + k0 + skk, bs + w * 1024);
        gload_lds16(Bte + brow1 + k0 + skk, bs + 4096 + w * 1024);
    };
    auto compute = [&](int buf) {
        bf16x8 af[4], bfr[4];
#pragma unroll
        for (int m = 0; m < 4; ++m)
            af[m] = *reinterpret_cast<const bf16x8*>(
                &Asm[buf][(wr * 64 + m * 16 + lrow) * 32 + lk8]);
#pragma unroll
        for (int n = 0; n < 4; ++n)
            bfr[n] = *reinterpret_cast<const bf16x8*>(
                &Bsm[buf][(wc * 64 + n * 16 + lrow) * 32 + lk8]);
#pragma unroll
        for (int m = 0; m < 4; ++m)
#pragma unroll
            for (int n = 0; n < 4; ++n)
                acc[m][n] = __builtin_amdgcn_mfma_f32_16x16x32_bf16(
                    af[m], bfr[n], acc[m][n], 0, 0, 0);
    };

    constexpr int NK = KD / 32;
    stage(0, 0);
    __syncthreads();              // drain vmcnt(0): buf0 ready
#pragma unroll 2
    for (int t = 1; t < NK; ++t) {
        stage(t & 1, t * 32);     // issue next-tile loads FIRST (latency hides under MFMA)
        compute((t - 1) & 1);
        __syncthreads();          // drains vmcnt(0): next buf ready, cur buf reusable
    }
    compute((NK - 1) & 1);

    // epilogue: C/D layout row=(lane>>4)*4+i, col=lane&15 (m89-verified)
    int lhi4 = (lane >> 4) * 4;
#pragma unroll
    for (int n = 0; n < 4; ++n) {
        int col = n0 + wc * 64 + n * 16 + lrow;
        float bv = 0.f;
        if constexpr (GELU) bv = bias[(size_t)e * ND + col];
#pragma unroll
        for (int m = 0; m < 4; ++m) {
            int rbase = wr * 64 + m * 16 + lhi4;
#pragma unroll
            for (int i = 0; i < 4; ++i) {
                int row = rbase + i;
                if (m0 + row < cnt) {
                    float v = acc[m][n][i];
                    if constexpr (GELU) {
                        v += bv;
                        v = 0.5f * v * (1.f + erff(v * 0.70710678118654752f));
                    }
                    outb[(size_t)(base + m0 + row) * ND + col] = f2bf(v);
                }
            }
        }
    }
}

// ---------------- combine: out[t] = sum_k w_k * (y[slot_k] + b2[e_k]) ----------------
__global__ __launch_bounds__(256) void combine_k(
        const int* __restrict__ tk_idx, const float* __restrict__ tk_w,
        const int* __restrict__ inv_slot, const u16* __restrict__ ybuf,
        const float* __restrict__ b2, float* __restrict__ out) {
    int gtid = blockIdx.x * 256 + threadIdx.x;
    int t = gtid >> 6;
    int lane = gtid & 63;
    int e0 = tk_idx[2 * t], e1 = tk_idx[2 * t + 1];
    float w0 = tk_w[2 * t], w1 = tk_w[2 * t + 1];
    int s0 = inv_slot[2 * t], s1 = inv_slot[2 * t + 1];

#pragma unroll
    for (int i = 0; i < 2; ++i) {
        int c = lane * 8 + i * 512;
        uint4 q0 = *reinterpret_cast<const uint4*>(ybuf + (size_t)s0 * HD + c);
        uint4 q1 = *reinterpret_cast<const uint4*>(ybuf + (size_t)s1 * HD + c);
        float y0[8] = {bf2f((u16)(q0.x&0xffff)), bf2f((u16)(q0.x>>16)),
                       bf2f((u16)(q0.y&0xffff)), bf2f((u16)(q0.y>>16)),
                       bf2f((u16)(q0.z&0xffff)), bf2f((u16)(q0.z>>16)),
                       bf2f((u16)(q0.w&0xffff)), bf2f((u16)(q0.w>>16))};
        float y1[8] = {bf2f((u16)(q1.x&0xffff)), bf2f((u16)(q1.x>>16)),
                       bf2f((u16)(q1.y&0xffff)), bf2f((u16)(q1.y>>16)),
                       bf2f((u16)(q1.z&0xffff)), bf2f((u16)(q1.z>>16)),
                       bf2f((u16)(q1.w&0xffff)), bf2f((u16)(q1.w>>16))};
        float r[8];
#pragma unroll
        for (int j = 0; j < 8; ++j) {
            float v0 = y0[j] + b2[e0 * HD + c + j];
            float v1 = y1[j] + b2[e1 * HD + c + j];
            r[j] = w0 * v0 + w1 * v1;
        }
        float* op = out + (size_t)t * HD + c;
        *reinterpret_cast<float4*>(op)     = make_float4(r[0], r[1], r[2], r[3]);
        *reinterpret_cast<float4*>(op + 4) = make_float4(r[4], r[5], r[6], r[7]);
    }
}

// ---------------- aux loss finalize ----------------
__global__ void finalize_k(const int* __restrict__ counts,
                           const float* __restrict__ sum_probs,
                           float* __restrict__ out_aux) {
    if (threadIdx.x == 0) {
        double s = 0.0;
        for (int e = 0; e < NE; ++e) s += (double)counts[e] * (double)sum_probs[e];
        out_aux[0] = (float)(s * (8.0 / (2.0 * (double)NTOK)));
    }
}

extern "C" void kernel_launch(void* const* d_in, const int* in_sizes, int n_in,
                              void* d_out, int out_size, void* d_ws, size_t ws_size,
                              hipStream_t stream) {
    const float* x   = (const float*)d_in[0];
    const float* gw  = (const float*)d_in[1];
    const float* W1  = (const float*)d_in[2];
    const float* b1  = (const float*)d_in[3];
    const float* W2  = (const float*)d_in[4];
    const float* b2  = (const float*)d_in[5];
    float* out = (float*)d_out;

    char* ws = (char*)d_ws;
    // meta block [0,512): counts@0, cursor@32, offsets@64, sum_probs@128
    int*   counts    = (int*)(ws + 0);
    int*   cursor    = (int*)(ws + 32);
    int*   offsets   = (int*)(ws + 64);
    float* sum_probs = (float*)(ws + 128);
    int*   tk_idx    = (int*)(ws + 512);                 // 32768 B
    float* tk_w      = (float*)(ws + 33280);             // 32768 B
    int*   slot_tok  = (int*)(ws + 66048);               // 32768 B
    int*   inv_slot  = (int*)(ws + 98816);               // 32768 B
    u16*   xb        = (u16*)(ws + 131584);              // 8,388,608 B
    u16*   W1t       = (u16*)(ws + 8520192);             // 33,554,432 B [ybuf aliases]
    u16*   W2t       = (u16*)(ws + 42074624);            // 33,554,432 B
    u16*   hbuf      = (u16*)(ws + 75629056);            // 34,078,720 B (padded rows)
    u16*   ybuf      = W1t;                              // W1t dead after gemm1
    // total = 109,707,776 B

    hipMemsetAsync(ws, 0, 512, stream);

    cvtT_k<HD, DD><<<dim3(DD / 32, HD / 32, NE), 256, 0, stream>>>(W1, W1t);
    cvtT_k<DD, HD><<<dim3(HD / 32, DD / 32, NE), 256, 0, stream>>>(W2, W2t);
    router_k<<<NTOK / 4, 256, 0, stream>>>(x, gw, xb, counts, sum_probs, tk_idx, tk_w);
    scan_k<<<1, 64, 0, stream>>>(counts, offsets);
    scatter_k<<<NTOK / 256, 256, 0, stream>>>(tk_idx, offsets, cursor, slot_tok, inv_slot);

    gemm_mfma_k<HD, DD, true, true><<<dim3(DD / 128, NTOK / 128, NE), 256, 0, stream>>>(
        xb, W1t, b1, counts, offsets, slot_tok, hbuf);
    gemm_mfma_k<DD, HD, false, false><<<dim3(HD / 128, NTOK / 128, NE), 256, 0, stream>>>(
        hbuf, W2t, nullptr, counts, offsets, slot_tok, ybuf);

    combine_k<<<NTOK / 4, 256, 0, stream>>>(tk_idx, tk_w, inv_slot, ybuf, b2, out);
    finalize_k<<<1, 64, 0, stream>>>(counts, sum_probs, out + (size_t)NTOK * HD);
}

// Round 4
// 281.436 us; speedup vs baseline: 1.0240x; 1.0240x over previous
//
#include <hip/hip_runtime.h>
#include <hip/hip_bf16.h>

#define NTOK 4096   // B*S
#define HD   1024   // hidden
#define DD   2048   // expert hidden
#define NE   8      // experts
#define SLOTS (2*NTOK)
#define SLOTS_PAD (SLOTS + 128)

typedef unsigned short u16;
typedef unsigned int   u32;
typedef __attribute__((ext_vector_type(8))) __bf16 bf16x8;
typedef __attribute__((ext_vector_type(4))) float  f32x4;

#define WAITV(N) asm volatile("s_waitcnt vmcnt(" #N ")" ::: "memory")
#define BAR()    __builtin_amdgcn_s_barrier()

__device__ __forceinline__ float bf2f(u16 u) {
    u32 v = ((u32)u) << 16;
    return __uint_as_float(v);
}
__device__ __forceinline__ u16 f2bf(float f) {
    __hip_bfloat16 h = __float2bfloat16(f);   // RTN
    return *reinterpret_cast<u16*>(&h);
}

__device__ __forceinline__ void gload_lds16(const void* g, void* l) {
    __builtin_amdgcn_global_load_lds(
        (__attribute__((address_space(1))) void*)g,
        (__attribute__((address_space(3))) void*)l,
        16, 0, 0);
}

// ---------------- convert + transpose weights: src [e][R][C] f32 -> dst [e][C][R] bf16
template<int R, int C>
__global__ __launch_bounds__(256) void cvtT_k(const float* __restrict__ src,
                                              u16* __restrict__ dst) {
    __shared__ u16 tile[32][33];
    int e  = blockIdx.z;
    int c0 = blockIdx.x * 32, r0 = blockIdx.y * 32;
    int tx = threadIdx.x & 31, ty = threadIdx.x >> 5;   // 32 x 8
    const float* s = src + (size_t)e * R * C;
    u16* d = dst + (size_t)e * C * R;
#pragma unroll
    for (int j = 0; j < 4; ++j) {
        int r = ty + j * 8;
        tile[r][tx] = f2bf(s[(size_t)(r0 + r) * C + c0 + tx]);
    }
    __syncthreads();
#pragma unroll
    for (int j = 0; j < 4; ++j) {
        int cc = ty + j * 8;
        d[(size_t)(c0 + cc) * R + r0 + tx] = tile[tx][cc];
    }
}

// ---------------- router (fused x->bf16 convert): 1 wave per token ----------------
__global__ __launch_bounds__(256) void router_k(
        const float* __restrict__ x, const float* __restrict__ gw,
        u16* __restrict__ xb,
        int* __restrict__ counts, float* __restrict__ sum_probs,
        int* __restrict__ tk_idx, float* __restrict__ tk_w) {
    __shared__ int   bcnt[NE];
    __shared__ float bprob[NE];
    int tid = threadIdx.x;
    if (tid < NE) { bcnt[tid] = 0; bprob[tid] = 0.f; }
    __syncthreads();

    int gtid = blockIdx.x * 256 + tid;
    int t    = gtid >> 6;
    int lane = gtid & 63;

    float acc[NE] = {0.f,0.f,0.f,0.f,0.f,0.f,0.f,0.f};
    const float* xr = x + (size_t)t * HD;
    u16* xbr = xb + (size_t)t * HD;
#pragma unroll
    for (int i = 0; i < HD / 64; ++i) {
        int h = lane + i * 64;
        float xv = xr[h];
        xbr[h] = f2bf(xv);   // fused bf16 convert
        const float4* g = reinterpret_cast<const float4*>(gw + (size_t)h * NE);
        float4 g0 = g[0], g1 = g[1];
        acc[0] = fmaf(xv, g0.x, acc[0]); acc[1] = fmaf(xv, g0.y, acc[1]);
        acc[2] = fmaf(xv, g0.z, acc[2]); acc[3] = fmaf(xv, g0.w, acc[3]);
        acc[4] = fmaf(xv, g1.x, acc[4]); acc[5] = fmaf(xv, g1.y, acc[5]);
        acc[6] = fmaf(xv, g1.z, acc[6]); acc[7] = fmaf(xv, g1.w, acc[7]);
    }
#pragma unroll
    for (int off = 32; off >= 1; off >>= 1) {
#pragma unroll
        for (int e = 0; e < NE; ++e) acc[e] += __shfl_xor(acc[e], off);
    }
    float m = acc[0];
#pragma unroll
    for (int e = 1; e < NE; ++e) m = fmaxf(m, acc[e]);
    float p[NE]; float s = 0.f;
#pragma unroll
    for (int e = 0; e < NE; ++e) { p[e] = expf(acc[e] - m); s += p[e]; }
    float inv = 1.f / s;

    int i1 = 0; float v1 = p[0];
#pragma unroll
    for (int e = 1; e < NE; ++e) if (p[e] > v1) { v1 = p[e]; i1 = e; }
    int i2 = -1; float v2 = -1.f;
#pragma unroll
    for (int e = 0; e < NE; ++e) if (e != i1 && p[e] > v2) { v2 = p[e]; i2 = e; }
    float wsum = v1 + v2;

    if (lane < NE) atomicAdd(&bprob[lane], p[lane] * inv);
    if (lane == 0) {
        atomicAdd(&bcnt[i1], 1);
        atomicAdd(&bcnt[i2], 1);
        tk_idx[2 * t]     = i1;  tk_idx[2 * t + 1] = i2;
        tk_w[2 * t]       = v1 / wsum;
        tk_w[2 * t + 1]   = v2 / wsum;
    }
    __syncthreads();
    if (tid < NE) {
        if (bcnt[tid]) atomicAdd(&counts[tid], bcnt[tid]);
        atomicAdd(&sum_probs[tid], bprob[tid]);
    }
}

// ---------------- exclusive scan over 8 experts ----------------
__global__ void scan_k(const int* __restrict__ counts, int* __restrict__ offsets) {
    if (threadIdx.x == 0) {
        int o = 0;
        for (int e = 0; e < NE; ++e) { offsets[e] = o; o += counts[e]; }
    }
}

// ---------------- scatter tokens into expert-grouped slots ----------------
__global__ __launch_bounds__(256) void scatter_k(
        const int* __restrict__ tk_idx, const int* __restrict__ offsets,
        int* __restrict__ cursor, int* __restrict__ slot_tok,
        int* __restrict__ inv_slot) {
    int t = blockIdx.x * 256 + threadIdx.x;
    if (t >= NTOK) return;
#pragma unroll
    for (int k = 0; k < 2; ++k) {
        int e = tk_idx[2 * t + k];
        int pos = atomicAdd(&cursor[e], 1);
        int s = offsets[e] + pos;
        slot_tok[s] = t;
        inv_slot[2 * t + k] = s;
    }
}

// ---------------- grouped MFMA GEMM, 3-deep counted-vmcnt pipeline ----------------
// C[m][n] = sum_k A[m][k] * Bt[n][k]  per expert.
// BM=128, BN=256, BK=64; 512 threads = 8 waves (2M x 4N), wave tile 64x64.
// LDS ring: 3 bufs x (A 16KB + B 32KB) = 144KB -> 1 block/CU, 2 waves/SIMD.
// T2 XOR swizzle (slot ^= row&7) on global-source + ds_read (rule 21).
// T4: raw s_barrier + counted vmcnt(12/6/0), loads stay in flight across barriers.
template<int KD, int ND, bool GATHER, bool GELU>
__global__ __launch_bounds__(512, 2) void gemm_pipe_k(
        const u16* __restrict__ A,      // GATHER: xb [NTOK][KD]; else hbuf [SLOTS_PAD][KD]
        const u16* __restrict__ Bt,     // [NE][ND][KD]
        const float* __restrict__ bias, // GELU: b1 [NE][ND]
        const int* __restrict__ counts, const int* __restrict__ offsets,
        const int* __restrict__ slot_tok,
        u16* __restrict__ outb) {       // [SLOTS_PAD][ND]
    int e   = blockIdx.z;
    int cnt = counts[e];
    int m0  = blockIdx.y * 128;
    if (m0 >= cnt) return;              // block-uniform exit (before any barrier)
    int n0   = blockIdx.x * 256;
    int base = offsets[e];

    // 3 * (8192 A + 16384 B) u16 = 147456 B; + ids = 147968 B <= 160 KiB
    __shared__ u16 smem[3 * 24576];
    __shared__ int ids[128];

    int tid  = threadIdx.x;
    int lane = tid & 63;
    int w    = tid >> 6;                // 8 waves
    int wr   = w >> 2, wc = w & 3;      // 2M x 4N
    int lrow = lane & 15, khi = lane >> 4;

    if constexpr (GATHER) {
        if (tid < 128) ids[tid] = (m0 + tid < cnt) ? slot_tok[base + m0 + tid] : 0;
    }
    __syncthreads();

    const u16* Bte = Bt + (size_t)e * ND * KD;
    int rl = tid >> 3;                  // 0..63: row within a 64-row staging round
    int sl = tid & 7;                   // 16B slot within 128B row
    int ssw = (sl ^ (rl & 7)) << 3;     // pre-swizzled k-elem offset (T2, global side)

    const u16 *ga0, *ga1, *gb0, *gb1, *gb2, *gb3;
    if constexpr (GATHER) {
        ga0 = A + (size_t)ids[rl]      * KD + ssw;
        ga1 = A + (size_t)ids[64 + rl] * KD + ssw;
    } else {
        ga0 = A + (size_t)(base + m0 + rl)      * KD + ssw;
        ga1 = A + (size_t)(base + m0 + rl + 64) * KD + ssw;
    }
    gb0 = Bte + (size_t)(n0 + rl)       * KD + ssw;
    gb1 = Bte + (size_t)(n0 + rl + 64)  * KD + ssw;
    gb2 = Bte + (size_t)(n0 + rl + 128) * KD + ssw;
    gb3 = Bte + (size_t)(n0 + rl + 192) * KD + ssw;

    f32x4 acc[4][4];
#pragma unroll
    for (int m = 0; m < 4; ++m)
#pragma unroll
        for (int n = 0; n < 4; ++n) acc[m][n] = {0.f, 0.f, 0.f, 0.f};

    // 6 gload_lds per wave per K-tile (vmcnt += 6)
    auto stage = [&](int buf, int k0) {
        char* as = (char*)smem + buf * 49152 + (size_t)w * 1024;  // wave-uniform base
        gload_lds16(ga0 + k0, as);
        gload_lds16(ga1 + k0, as + 8192);
        gload_lds16(gb0 + k0, as + 16384);
        gload_lds16(gb1 + k0, as + 24576);
        gload_lds16(gb2 + k0, as + 32768);
        gload_lds16(gb3 + k0, as + 40960);
    };
    auto compute = [&](int buf) {
        const u16* As = smem + buf * 24576;
        const u16* Bs = As + 8192;
#pragma unroll
        for (int kk = 0; kk < 2; ++kk) {
            int slot = kk * 4 + khi;
            bf16x8 af[4], bv[4];
#pragma unroll
            for (int m = 0; m < 4; ++m) {
                int r = wr * 64 + m * 16 + lrow;
                af[m] = *reinterpret_cast<const bf16x8*>(
                    &As[r * 64 + ((slot ^ (r & 7)) << 3)]);
            }
#pragma unroll
            for (int n = 0; n < 4; ++n) {
                int r = wc * 64 + n * 16 + lrow;
                bv[n] = *reinterpret_cast<const bf16x8*>(
                    &Bs[r * 64 + ((slot ^ (r & 7)) << 3)]);
            }
            __builtin_amdgcn_s_setprio(1);
#pragma unroll
            for (int m = 0; m < 4; ++m)
#pragma unroll
                for (int n = 0; n < 4; ++n)
                    acc[m][n] = __builtin_amdgcn_mfma_f32_16x16x32_bf16(
                        af[m], bv[n], acc[m][n], 0, 0, 0);
            __builtin_amdgcn_s_setprio(0);
        }
    };

    constexpr int NK = KD / 64;         // 16 or 32 (>= 4)
    stage(0, 0); stage(1, 64); stage(2, 128);   // 18 loads in flight

    int buf = 0;
#pragma unroll 1
    for (int t = 0; t < NK - 3; ++t) {
        WAITV(12);                      // tile t's 6 loads done (12 newer still flying)
        BAR();                          // all waves' tile-t loads done
        compute(buf);
        BAR();                          // all waves done reading buf -> reusable
        stage(buf, (t + 3) * 64);
        buf = (buf == 2) ? 0 : buf + 1;
    }
    WAITV(12); BAR(); compute(buf); BAR(); buf = (buf == 2) ? 0 : buf + 1;  // t=NK-3
    WAITV(6);  BAR(); compute(buf); BAR(); buf = (buf == 2) ? 0 : buf + 1;  // t=NK-2
    WAITV(0);  BAR(); compute(buf);                                         // t=NK-1
    BAR();   // smem now reusable for epilogue packing

    // ---- epilogue: pack wave's 64x64 C-tile via LDS (stride 72 u16 = 144B,
    //      bank-rotated), then coalesced 16B/lane stores ----
    u16* patch = smem + w * (64 * 72);
    float bvals[4];
    if constexpr (GELU) {
#pragma unroll
        for (int n = 0; n < 4; ++n)
            bvals[n] = bias[(size_t)e * ND + n0 + wc * 64 + n * 16 + lrow];
    }
#pragma unroll
    for (int m = 0; m < 4; ++m)
#pragma unroll
        for (int n = 0; n < 4; ++n)
#pragma unroll
            for (int i = 0; i < 4; ++i) {
                float v = acc[m][n][i];
                if constexpr (GELU) {
                    v += bvals[n];
                    v = 0.5f * v * (1.f + erff(v * 0.70710678118654752f));
                }
                int row = m * 16 + khi * 4 + i;   // wave-local row
                int col = n * 16 + lrow;          // wave-local col
                patch[row * 72 + col] = f2bf(v);
            }
    BAR();
    int rl8 = lane >> 3, sl8 = lane & 7;
#pragma unroll
    for (int rd = 0; rd < 8; ++rd) {
        int row  = rd * 8 + rl8;                  // wave-local
        int grow = m0 + wr * 64 + row;
        if (grow < cnt) {
            uint4 q = *reinterpret_cast<const uint4*>(&patch[row * 72 + sl8 * 8]);
            *reinterpret_cast<uint4*>(
                outb + (size_t)(base + grow) * ND + n0 + wc * 64 + sl8 * 8) = q;
        }
    }
}

// ---------------- combine: out[t] = sum_k w_k * (y[slot_k] + b2[e_k]) ----------------
__global__ __launch_bounds__(256) void combine_k(
        const int* __restrict__ tk_idx, const float* __restrict__ tk_w,
        const int* __restrict__ inv_slot, const u16* __restrict__ ybuf,
        const float* __restrict__ b2, float* __restrict__ out) {
    int gtid = blockIdx.x * 256 + threadIdx.x;
    int t = gtid >> 6;
    int lane = gtid & 63;
    int e0 = tk_idx[2 * t], e1 = tk_idx[2 * t + 1];
    float w0 = tk_w[2 * t], w1 = tk_w[2 * t + 1];
    int s0 = inv_slot[2 * t], s1 = inv_slot[2 * t + 1];

#pragma unroll
    for (int i = 0; i < 2; ++i) {
        int c = lane * 8 + i * 512;
        uint4 q0 = *reinterpret_cast<const uint4*>(ybuf + (size_t)s0 * HD + c);
        uint4 q1 = *reinterpret_cast<const uint4*>(ybuf + (size_t)s1 * HD + c);
        float y0[8] = {bf2f((u16)(q0.x&0xffff)), bf2f((u16)(q0.x>>16)),
                       bf2f((u16)(q0.y&0xffff)), bf2f((u16)(q0.y>>16)),
                       bf2f((u16)(q0.z&0xffff)), bf2f((u16)(q0.z>>16)),
                       bf2f((u16)(q0.w&0xffff)), bf2f((u16)(q0.w>>16))};
        float y1[8] = {bf2f((u16)(q1.x&0xffff)), bf2f((u16)(q1.x>>16)),
                       bf2f((u16)(q1.y&0xffff)), bf2f((u16)(q1.y>>16)),
                       bf2f((u16)(q1.z&0xffff)), bf2f((u16)(q1.z>>16)),
                       bf2f((u16)(q1.w&0xffff)), bf2f((u16)(q1.w>>16))};
        float r[8];
#pragma unroll
        for (int j = 0; j < 8; ++j) {
            float v0 = y0[j] + b2[e0 * HD + c + j];
            float v1 = y1[j] + b2[e1 * HD + c + j];
            r[j] = w0 * v0 + w1 * v1;
        }
        float* op = out + (size_t)t * HD + c;
        *reinterpret_cast<float4*>(op)     = make_float4(r[0], r[1], r[2], r[3]);
        *reinterpret_cast<float4*>(op + 4) = make_float4(r[4], r[5], r[6], r[7]);
    }
}

// ---------------- aux loss finalize ----------------
__global__ void finalize_k(const int* __restrict__ counts,
                           const float* __restrict__ sum_probs,
                           float* __restrict__ out_aux) {
    if (threadIdx.x == 0) {
        double s = 0.0;
        for (int e = 0; e < NE; ++e) s += (double)counts[e] * (double)sum_probs[e];
        out_aux[0] = (float)(s * (8.0 / (2.0 * (double)NTOK)));
    }
}

extern "C" void kernel_launch(void* const* d_in, const int* in_sizes, int n_in,
                              void* d_out, int out_size, void* d_ws, size_t ws_size,
                              hipStream_t stream) {
    const float* x   = (const float*)d_in[0];
    const float* gw  = (const float*)d_in[1];
    const float* W1  = (const float*)d_in[2];
    const float* b1  = (const float*)d_in[3];
    const float* W2  = (const float*)d_in[4];
    const float* b2  = (const float*)d_in[5];
    float* out = (float*)d_out;

    char* ws = (char*)d_ws;
    // meta block [0,512): counts@0, cursor@32, offsets@64, sum_probs@128
    int*   counts    = (int*)(ws + 0);
    int*   cursor    = (int*)(ws + 32);
    int*   offsets   = (int*)(ws + 64);
    float* sum_probs = (float*)(ws + 128);
    int*   tk_idx    = (int*)(ws + 512);                 // 32768 B
    float* tk_w      = (float*)(ws + 33280);             // 32768 B
    int*   slot_tok  = (int*)(ws + 66048);               // 32768 B
    int*   inv_slot  = (int*)(ws + 98816);               // 32768 B
    u16*   xb        = (u16*)(ws + 131584);              // 8,388,608 B
    u16*   W1t       = (u16*)(ws + 8520192);             // 33,554,432 B [ybuf aliases]
    u16*   W2t       = (u16*)(ws + 42074624);            // 33,554,432 B
    u16*   hbuf      = (u16*)(ws + 75629056);            // 34,078,720 B (SLOTS_PAD rows)
    u16*   ybuf      = W1t;                              // W1t dead after gemm1
    // total = 109,707,776 B

    hipMemsetAsync(ws, 0, 512, stream);

    cvtT_k<HD, DD><<<dim3(DD / 32, HD / 32, NE), 256, 0, stream>>>(W1, W1t);
    cvtT_k<DD, HD><<<dim3(HD / 32, DD / 32, NE), 256, 0, stream>>>(W2, W2t);
    router_k<<<NTOK / 4, 256, 0, stream>>>(x, gw, xb, counts, sum_probs, tk_idx, tk_w);
    scan_k<<<1, 64, 0, stream>>>(counts, offsets);
    scatter_k<<<NTOK / 256, 256, 0, stream>>>(tk_idx, offsets, cursor, slot_tok, inv_slot);

    gemm_pipe_k<HD, DD, true, true><<<dim3(DD / 256, NTOK / 128, NE), 512, 0, stream>>>(
        xb, W1t, b1, counts, offsets, slot_tok, hbuf);
    gemm_pipe_k<DD, HD, false, false><<<dim3(HD / 256, NTOK / 128, NE), 512, 0, stream>>>(
        hbuf, W2t, nullptr, counts, offsets, slot_tok, ybuf);

    combine_k<<<NTOK / 4, 256, 0, stream>>>(tk_idx, tk_w, inv_slot, ybuf, b2, out);
    finalize_k<<<1, 64, 0, stream>>>(counts, sum_probs, out + (size_t)NTOK * HD);
}

// Round 5
// 280.723 us; speedup vs baseline: 1.0266x; 1.0025x over previous
//
#include <hip/hip_runtime.h>
#include <hip/hip_bf16.h>

#define NTOK 4096   // B*S
#define HD   1024   // hidden
#define DD   2048   // expert hidden
#define NE   8      // experts
#define SLOTS (2*NTOK)
#define SLOTS_PAD (SLOTS + 128)

typedef unsigned short u16;
typedef unsigned int   u32;
typedef __attribute__((ext_vector_type(8))) __bf16 bf16x8;
typedef __attribute__((ext_vector_type(4))) float  f32x4;

#define WAITV(N) asm volatile("s_waitcnt vmcnt(" #N ")" ::: "memory")
#define BAR()    __builtin_amdgcn_s_barrier()

__device__ __forceinline__ float bf2f(u16 u) {
    u32 v = ((u32)u) << 16;
    return __uint_as_float(v);
}
__device__ __forceinline__ u16 f2bf(float f) {
    __hip_bfloat16 h = __float2bfloat16(f);   // RTN
    return *reinterpret_cast<u16*>(&h);
}

__device__ __forceinline__ void gload_lds16(const void* g, void* l) {
    __builtin_amdgcn_global_load_lds(
        (__attribute__((address_space(1))) void*)g,
        (__attribute__((address_space(3))) void*)l,
        16, 0, 0);
}

// ---------------- convert + transpose weights: src [e][R][C] f32 -> dst [e][C][R] bf16
template<int R, int C>
__global__ __launch_bounds__(256) void cvtT_k(const float* __restrict__ src,
                                              u16* __restrict__ dst) {
    __shared__ u16 tile[32][33];
    int e  = blockIdx.z;
    int c0 = blockIdx.x * 32, r0 = blockIdx.y * 32;
    int tx = threadIdx.x & 31, ty = threadIdx.x >> 5;   // 32 x 8
    const float* s = src + (size_t)e * R * C;
    u16* d = dst + (size_t)e * C * R;
#pragma unroll
    for (int j = 0; j < 4; ++j) {
        int r = ty + j * 8;
        tile[r][tx] = f2bf(s[(size_t)(r0 + r) * C + c0 + tx]);
    }
    __syncthreads();
#pragma unroll
    for (int j = 0; j < 4; ++j) {
        int cc = ty + j * 8;
        d[(size_t)(c0 + cc) * R + r0 + tx] = tile[tx][cc];
    }
}

// ---------------- router (fused x->bf16 convert): 1 wave per token ----------------
__global__ __launch_bounds__(256) void router_k(
        const float* __restrict__ x, const float* __restrict__ gw,
        u16* __restrict__ xb,
        int* __restrict__ counts, float* __restrict__ sum_probs,
        int* __restrict__ tk_idx, float* __restrict__ tk_w) {
    __shared__ int   bcnt[NE];
    __shared__ float bprob[NE];
    int tid = threadIdx.x;
    if (tid < NE) { bcnt[tid] = 0; bprob[tid] = 0.f; }
    __syncthreads();

    int gtid = blockIdx.x * 256 + tid;
    int t    = gtid >> 6;
    int lane = gtid & 63;

    float acc[NE] = {0.f,0.f,0.f,0.f,0.f,0.f,0.f,0.f};
    const float* xr = x + (size_t)t * HD;
    u16* xbr = xb + (size_t)t * HD;
#pragma unroll
    for (int i = 0; i < HD / 64; ++i) {
        int h = lane + i * 64;
        float xv = xr[h];
        xbr[h] = f2bf(xv);   // fused bf16 convert
        const float4* g = reinterpret_cast<const float4*>(gw + (size_t)h * NE);
        float4 g0 = g[0], g1 = g[1];
        acc[0] = fmaf(xv, g0.x, acc[0]); acc[1] = fmaf(xv, g0.y, acc[1]);
        acc[2] = fmaf(xv, g0.z, acc[2]); acc[3] = fmaf(xv, g0.w, acc[3]);
        acc[4] = fmaf(xv, g1.x, acc[4]); acc[5] = fmaf(xv, g1.y, acc[5]);
        acc[6] = fmaf(xv, g1.z, acc[6]); acc[7] = fmaf(xv, g1.w, acc[7]);
    }
#pragma unroll
    for (int off = 32; off >= 1; off >>= 1) {
#pragma unroll
        for (int e = 0; e < NE; ++e) acc[e] += __shfl_xor(acc[e], off);
    }
    float m = acc[0];
#pragma unroll
    for (int e = 1; e < NE; ++e) m = fmaxf(m, acc[e]);
    float p[NE]; float s = 0.f;
#pragma unroll
    for (int e = 0; e < NE; ++e) { p[e] = expf(acc[e] - m); s += p[e]; }
    float inv = 1.f / s;

    int i1 = 0; float v1 = p[0];
#pragma unroll
    for (int e = 1; e < NE; ++e) if (p[e] > v1) { v1 = p[e]; i1 = e; }
    int i2 = -1; float v2 = -1.f;
#pragma unroll
    for (int e = 0; e < NE; ++e) if (e != i1 && p[e] > v2) { v2 = p[e]; i2 = e; }
    float wsum = v1 + v2;

    if (lane < NE) atomicAdd(&bprob[lane], p[lane] * inv);
    if (lane == 0) {
        atomicAdd(&bcnt[i1], 1);
        atomicAdd(&bcnt[i2], 1);
        tk_idx[2 * t]     = i1;  tk_idx[2 * t + 1] = i2;
        tk_w[2 * t]       = v1 / wsum;
        tk_w[2 * t + 1]   = v2 / wsum;
    }
    __syncthreads();
    if (tid < NE) {
        if (bcnt[tid]) atomicAdd(&counts[tid], bcnt[tid]);
        atomicAdd(&sum_probs[tid], bprob[tid]);
    }
}

// ---------------- exclusive scan over 8 experts ----------------
__global__ void scan_k(const int* __restrict__ counts, int* __restrict__ offsets) {
    if (threadIdx.x == 0) {
        int o = 0;
        for (int e = 0; e < NE; ++e) { offsets[e] = o; o += counts[e]; }
    }
}

// ---------------- scatter tokens into expert-grouped slots ----------------
__global__ __launch_bounds__(256) void scatter_k(
        const int* __restrict__ tk_idx, const int* __restrict__ offsets,
        int* __restrict__ cursor, int* __restrict__ slot_tok,
        int* __restrict__ inv_slot) {
    int t = blockIdx.x * 256 + threadIdx.x;
    if (t >= NTOK) return;
#pragma unroll
    for (int k = 0; k < 2; ++k) {
        int e = tk_idx[2 * t + k];
        int pos = atomicAdd(&cursor[e], 1);
        int s = offsets[e] + pos;
        slot_tok[s] = t;
        inv_slot[2 * t + k] = s;
    }
}

// ---------------- grouped MFMA GEMM: 128x128xBK64, 4 waves, fine-phase pipeline ----
// Per K-tile: two k-half phases. Phase = {WAITV(4); s_barrier; 8 ds_read_b128;
// issue 4 gload_lds (next tile, same k-half, other dbuf); 16 MFMA w/ setprio}.
// LDS: 2 dbuf x {A:[2][128][32], B:[2][128][32]} u16 = 64KB -> 2 blocks/CU (TLP).
// 64B LDS rows => frag reads are contiguous 1KB/wave: conflict-free, no swizzle.
template<int KD, bool GATHER, bool GELU>
__global__ __launch_bounds__(256, 2) void gemm_ph_k(
        const u16* __restrict__ A,      // GATHER: xb [NTOK][KD]; else hbuf [SLOTS_PAD][KD]
        const u16* __restrict__ Bt,     // [NE][ND][KD] with ND = out cols
        const float* __restrict__ bias, // GELU: b1 [NE][ND]
        const int* __restrict__ counts, const int* __restrict__ offsets,
        const int* __restrict__ slot_tok,
        u16* __restrict__ outb, int ND) {
    int e   = blockIdx.z;
    int cnt = counts[e];
    int m0  = blockIdx.y * 128;
    if (m0 >= cnt) return;              // block-uniform exit (before any barrier)
    int n0   = blockIdx.x * 128;
    int base = offsets[e];

    // regions of 4096 u16 (8KB): [buf][mat][kk] ; total 8 regions = 64KB
    __shared__ u16 smem[8 * 4096];
    __shared__ int ids[128];

    int tid  = threadIdx.x;
    int lane = tid & 63;
    int w    = tid >> 6;                // 4 waves
    int wr   = w >> 1, wc = w & 1;      // 2M x 2N, wave tile 64x64
    int lrow = lane & 15, khi = lane >> 4;

    if constexpr (GATHER) {
        if (tid < 128) ids[tid] = (m0 + tid < cnt) ? slot_tok[base + m0 + tid] : 0;
    }
    __syncthreads();

    const u16* Bte = Bt + (size_t)e * ND * KD;
    int srow = tid >> 2;                // 0..63 staging row (per round)
    int scol = (tid & 3) * 8;           // k-elem offset within 32-wide k-half

    // global row pointers for the two 64-row staging rounds
    const u16 *ga[2], *gb[2];
    if constexpr (GATHER) {
        ga[0] = A + (size_t)ids[srow]      * KD + scol;
        ga[1] = A + (size_t)ids[64 + srow] * KD + scol;
    } else {
        ga[0] = A + (size_t)(base + m0 + srow)      * KD + scol;
        ga[1] = A + (size_t)(base + m0 + srow + 64) * KD + scol;
    }
    gb[0] = Bte + (size_t)(n0 + srow)      * KD + scol;
    gb[1] = Bte + (size_t)(n0 + srow + 64) * KD + scol;

    f32x4 acc[4][4];
#pragma unroll
    for (int m = 0; m < 4; ++m)
#pragma unroll
        for (int n = 0; n < 4; ++n) acc[m][n] = {0.f, 0.f, 0.f, 0.f};

    // stage group (buf, tile t, k-half kk): 4 gload_lds (A r0,r1; B r0,r1)
    auto stageg = [&](int buf, int t, int kk) {
        int koff = t * 64 + kk * 32;
        u16* abase = smem + ((buf * 2 + 0) * 2 + kk) * 4096 + tid * 8;
        u16* bbase = smem + ((buf * 2 + 1) * 2 + kk) * 4096 + tid * 8;
        gload_lds16(ga[0] + koff, abase);
        gload_lds16(ga[1] + koff, abase + 2048);
        gload_lds16(gb[0] + koff, bbase);
        gload_lds16(gb[1] + koff, bbase + 2048);
    };
    // frag reads + 16 MFMA for (buf, kk)
    auto computeg = [&](int buf, int kk) {
        const u16* As = smem + ((buf * 2 + 0) * 2 + kk) * 4096;
        const u16* Bs = smem + ((buf * 2 + 1) * 2 + kk) * 4096;
        bf16x8 af[4], bv[4];
#pragma unroll
        for (int m = 0; m < 4; ++m)
            af[m] = *reinterpret_cast<const bf16x8*>(
                &As[(wr * 64 + m * 16 + lrow) * 32 + khi * 8]);
#pragma unroll
        for (int n = 0; n < 4; ++n)
            bv[n] = *reinterpret_cast<const bf16x8*>(
                &Bs[(wc * 64 + n * 16 + lrow) * 32 + khi * 8]);
        __builtin_amdgcn_s_setprio(1);
#pragma unroll
        for (int m = 0; m < 4; ++m)
#pragma unroll
            for (int n = 0; n < 4; ++n)
                acc[m][n] = __builtin_amdgcn_mfma_f32_16x16x32_bf16(
                    af[m], bv[n], acc[m][n], 0, 0, 0);
        __builtin_amdgcn_s_setprio(0);
    };

    constexpr int NK = KD / 64;
    stageg(0, 0, 0); stageg(0, 0, 1);   // 8 loads in flight

#pragma unroll 1
    for (int t = 0; t < NK - 1; ++t) {
        int b = t & 1;
        WAITV(4); BAR();                // (t,k0) landed block-wide; (t,k1) in flight
        stageg(b ^ 1, t + 1, 0);
        computeg(b, 0);
        WAITV(4); BAR();                // (t,k1) landed; (t+1,k0) in flight
        stageg(b ^ 1, t + 1, 1);
        computeg(b, 1);
    }
    {   // tail tile NK-1: no further staging
        int b = (NK - 1) & 1;
        WAITV(4); BAR();
        computeg(b, 0);
        WAITV(0); BAR();
        computeg(b, 1);
    }
    BAR();   // all frag reads retired -> smem reusable for epilogue

    // ---- epilogue: pack wave's 64x64 C-tile via LDS (stride 72 u16), then
    //      coalesced 16B/lane stores ----
    u16* patch = smem + w * (64 * 72);
    float bvals[4];
    if constexpr (GELU) {
#pragma unroll
        for (int n = 0; n < 4; ++n)
            bvals[n] = bias[(size_t)e * ND + n0 + wc * 64 + n * 16 + lrow];
    }
#pragma unroll
    for (int m = 0; m < 4; ++m)
#pragma unroll
        for (int n = 0; n < 4; ++n)
#pragma unroll
            for (int i = 0; i < 4; ++i) {
                float v = acc[m][n][i];
                if constexpr (GELU) {
                    v += bvals[n];
                    v = 0.5f * v * (1.f + erff(v * 0.70710678118654752f));
                }
                int row = m * 16 + khi * 4 + i;   // wave-local row
                int col = n * 16 + lrow;          // wave-local col
                patch[row * 72 + col] = f2bf(v);
            }
    BAR();
    int rl8 = lane >> 3, sl8 = lane & 7;
#pragma unroll
    for (int rd = 0; rd < 8; ++rd) {
        int row  = rd * 8 + rl8;                  // wave-local
        int grow = m0 + wr * 64 + row;
        if (grow < cnt) {
            uint4 q = *reinterpret_cast<const uint4*>(&patch[row * 72 + sl8 * 8]);
            *reinterpret_cast<uint4*>(
                outb + (size_t)(base + grow) * ND + n0 + wc * 64 + sl8 * 8) = q;
        }
    }
}

// ---------------- combine: out[t] = sum_k w_k * (y[slot_k] + b2[e_k]) ----------------
__global__ __launch_bounds__(256) void combine_k(
        const int* __restrict__ tk_idx, const float* __restrict__ tk_w,
        const int* __restrict__ inv_slot, const u16* __restrict__ ybuf,
        const float* __restrict__ b2, float* __restrict__ out) {
    int gtid = blockIdx.x * 256 + threadIdx.x;
    int t = gtid >> 6;
    int lane = gtid & 63;
    int e0 = tk_idx[2 * t], e1 = tk_idx[2 * t + 1];
    float w0 = tk_w[2 * t], w1 = tk_w[2 * t + 1];
    int s0 = inv_slot[2 * t], s1 = inv_slot[2 * t + 1];

#pragma unroll
    for (int i = 0; i < 2; ++i) {
        int c = lane * 8 + i * 512;
        uint4 q0 = *reinterpret_cast<const uint4*>(ybuf + (size_t)s0 * HD + c);
        uint4 q1 = *reinterpret_cast<const uint4*>(ybuf + (size_t)s1 * HD + c);
        float y0[8] = {bf2f((u16)(q0.x&0xffff)), bf2f((u16)(q0.x>>16)),
                       bf2f((u16)(q0.y&0xffff)), bf2f((u16)(q0.y>>16)),
                       bf2f((u16)(q0.z&0xffff)), bf2f((u16)(q0.z>>16)),
                       bf2f((u16)(q0.w&0xffff)), bf2f((u16)(q0.w>>16))};
        float y1[8] = {bf2f((u16)(q1.x&0xffff)), bf2f((u16)(q1.x>>16)),
                       bf2f((u16)(q1.y&0xffff)), bf2f((u16)(q1.y>>16)),
                       bf2f((u16)(q1.z&0xffff)), bf2f((u16)(q1.z>>16)),
                       bf2f((u16)(q1.w&0xffff)), bf2f((u16)(q1.w>>16))};
        float r[8];
#pragma unroll
        for (int j = 0; j < 8; ++j) {
            float v0 = y0[j] + b2[e0 * HD + c + j];
            float v1 = y1[j] + b2[e1 * HD + c + j];
            r[j] = w0 * v0 + w1 * v1;
        }
        float* op = out + (size_t)t * HD + c;
        *reinterpret_cast<float4*>(op)     = make_float4(r[0], r[1], r[2], r[3]);
        *reinterpret_cast<float4*>(op + 4) = make_float4(r[4], r[5], r[6], r[7]);
    }
}

// ---------------- aux loss finalize ----------------
__global__ void finalize_k(const int* __restrict__ counts,
                           const float* __restrict__ sum_probs,
                           float* __restrict__ out_aux) {
    if (threadIdx.x == 0) {
        double s = 0.0;
        for (int e = 0; e < NE; ++e) s += (double)counts[e] * (double)sum_probs[e];
        out_aux[0] = (float)(s * (8.0 / (2.0 * (double)NTOK)));
    }
}

extern "C" void kernel_launch(void* const* d_in, const int* in_sizes, int n_in,
                              void* d_out, int out_size, void* d_ws, size_t ws_size,
                              hipStream_t stream) {
    const float* x   = (const float*)d_in[0];
    const float* gw  = (const float*)d_in[1];
    const float* W1  = (const float*)d_in[2];
    const float* b1  = (const float*)d_in[3];
    const float* W2  = (const float*)d_in[4];
    const float* b2  = (const float*)d_in[5];
    float* out = (float*)d_out;

    char* ws = (char*)d_ws;
    // meta block [0,512): counts@0, cursor@32, offsets@64, sum_probs@128
    int*   counts    = (int*)(ws + 0);
    int*   cursor    = (int*)(ws + 32);
    int*   offsets   = (int*)(ws + 64);
    float* sum_probs = (float*)(ws + 128);
    int*   tk_idx    = (int*)(ws + 512);                 // 32768 B
    float* tk_w      = (float*)(ws + 33280);             // 32768 B
    int*   slot_tok  = (int*)(ws + 66048);               // 32768 B
    int*   inv_slot  = (int*)(ws + 98816);               // 32768 B
    u16*   xb        = (u16*)(ws + 131584);              // 8,388,608 B
    u16*   W1t       = (u16*)(ws + 8520192);             // 33,554,432 B [ybuf aliases]
    u16*   W2t       = (u16*)(ws + 42074624);            // 33,554,432 B
    u16*   hbuf      = (u16*)(ws + 75629056);            // 34,078,720 B (SLOTS_PAD rows)
    u16*   ybuf      = W1t;                              // W1t dead after gemm1
    // total = 109,707,776 B

    hipMemsetAsync(ws, 0, 512, stream);

    cvtT_k<HD, DD><<<dim3(DD / 32, HD / 32, NE), 256, 0, stream>>>(W1, W1t);
    cvtT_k<DD, HD><<<dim3(HD / 32, DD / 32, NE), 256, 0, stream>>>(W2, W2t);
    router_k<<<NTOK / 4, 256, 0, stream>>>(x, gw, xb, counts, sum_probs, tk_idx, tk_w);
    scan_k<<<1, 64, 0, stream>>>(counts, offsets);
    scatter_k<<<NTOK / 256, 256, 0, stream>>>(tk_idx, offsets, cursor, slot_tok, inv_slot);

    gemm_ph_k<HD, true, true><<<dim3(DD / 128, NTOK / 128, NE), 256, 0, stream>>>(
        xb, W1t, b1, counts, offsets, slot_tok, hbuf, DD);
    gemm_ph_k<DD, false, false><<<dim3(HD / 128, NTOK / 128, NE), 256, 0, stream>>>(
        hbuf, W2t, nullptr, counts, offsets, slot_tok, ybuf, HD);

    combine_k<<<NTOK / 4, 256, 0, stream>>>(tk_idx, tk_w, inv_slot, ybuf, b2, out);
    finalize_k<<<1, 64, 0, stream>>>(counts, sum_probs, out + (size_t)NTOK * HD);
}

// Round 6
// 275.691 us; speedup vs baseline: 1.0453x; 1.0183x over previous
//
#include <hip/hip_runtime.h>
#include <hip/hip_bf16.h>

#define NTOK 4096   // B*S
#define HD   1024   // hidden
#define DD   2048   // expert hidden
#define NE   8      // experts
#define SLOTS (2*NTOK)
#define SLOTS_PAD (SLOTS + 128)

typedef unsigned short u16;
typedef unsigned int   u32;
typedef __attribute__((ext_vector_type(8))) __bf16 bf16x8;
typedef __attribute__((ext_vector_type(4))) float  f32x4;

__device__ __forceinline__ float bf2f(u16 u) {
    u32 v = ((u32)u) << 16;
    return __uint_as_float(v);
}
__device__ __forceinline__ u16 f2bf(float f) {
    __hip_bfloat16 h = __float2bfloat16(f);   // RTN
    return *reinterpret_cast<u16*>(&h);
}

__device__ __forceinline__ void gload_lds16(const void* g, void* l) {
    __builtin_amdgcn_global_load_lds(
        (__attribute__((address_space(1))) void*)g,
        (__attribute__((address_space(3))) void*)l,
        16, 0, 0);
}

// ---------------- convert + transpose weights: src [e][R][C] f32 -> dst [e][C][R] bf16
template<int R, int C>
__global__ __launch_bounds__(256) void cvtT_k(const float* __restrict__ src,
                                              u16* __restrict__ dst) {
    __shared__ u16 tile[32][33];
    int e  = blockIdx.z;
    int c0 = blockIdx.x * 32, r0 = blockIdx.y * 32;
    int tx = threadIdx.x & 31, ty = threadIdx.x >> 5;   // 32 x 8
    const float* s = src + (size_t)e * R * C;
    u16* d = dst + (size_t)e * C * R;
#pragma unroll
    for (int j = 0; j < 4; ++j) {
        int r = ty + j * 8;
        tile[r][tx] = f2bf(s[(size_t)(r0 + r) * C + c0 + tx]);
    }
    __syncthreads();
#pragma unroll
    for (int j = 0; j < 4; ++j) {
        int cc = ty + j * 8;
        d[(size_t)(c0 + cc) * R + r0 + tx] = tile[tx][cc];
    }
}

// ---------------- router (fused x->bf16 convert): 1 wave per token ----------------
__global__ __launch_bounds__(256) void router_k(
        const float* __restrict__ x, const float* __restrict__ gw,
        u16* __restrict__ xb,
        int* __restrict__ counts, float* __restrict__ sum_probs,
        int* __restrict__ tk_idx, float* __restrict__ tk_w) {
    __shared__ int   bcnt[NE];
    __shared__ float bprob[NE];
    int tid = threadIdx.x;
    if (tid < NE) { bcnt[tid] = 0; bprob[tid] = 0.f; }
    __syncthreads();

    int gtid = blockIdx.x * 256 + tid;
    int t    = gtid >> 6;
    int lane = gtid & 63;

    float acc[NE] = {0.f,0.f,0.f,0.f,0.f,0.f,0.f,0.f};
    const float* xr = x + (size_t)t * HD;
    u16* xbr = xb + (size_t)t * HD;
#pragma unroll
    for (int i = 0; i < HD / 64; ++i) {
        int h = lane + i * 64;
        float xv = xr[h];
        xbr[h] = f2bf(xv);   // fused bf16 convert
        const float4* g = reinterpret_cast<const float4*>(gw + (size_t)h * NE);
        float4 g0 = g[0], g1 = g[1];
        acc[0] = fmaf(xv, g0.x, acc[0]); acc[1] = fmaf(xv, g0.y, acc[1]);
        acc[2] = fmaf(xv, g0.z, acc[2]); acc[3] = fmaf(xv, g0.w, acc[3]);
        acc[4] = fmaf(xv, g1.x, acc[4]); acc[5] = fmaf(xv, g1.y, acc[5]);
        acc[6] = fmaf(xv, g1.z, acc[6]); acc[7] = fmaf(xv, g1.w, acc[7]);
    }
#pragma unroll
    for (int off = 32; off >= 1; off >>= 1) {
#pragma unroll
        for (int e = 0; e < NE; ++e) acc[e] += __shfl_xor(acc[e], off);
    }
    float m = acc[0];
#pragma unroll
    for (int e = 1; e < NE; ++e) m = fmaxf(m, acc[e]);
    float p[NE]; float s = 0.f;
#pragma unroll
    for (int e = 0; e < NE; ++e) { p[e] = expf(acc[e] - m); s += p[e]; }
    float inv = 1.f / s;

    int i1 = 0; float v1 = p[0];
#pragma unroll
    for (int e = 1; e < NE; ++e) if (p[e] > v1) { v1 = p[e]; i1 = e; }
    int i2 = -1; float v2 = -1.f;
#pragma unroll
    for (int e = 0; e < NE; ++e) if (e != i1 && p[e] > v2) { v2 = p[e]; i2 = e; }
    float wsum = v1 + v2;

    if (lane < NE) atomicAdd(&bprob[lane], p[lane] * inv);
    if (lane == 0) {
        atomicAdd(&bcnt[i1], 1);
        atomicAdd(&bcnt[i2], 1);
        tk_idx[2 * t]     = i1;  tk_idx[2 * t + 1] = i2;
        tk_w[2 * t]       = v1 / wsum;
        tk_w[2 * t + 1]   = v2 / wsum;
    }
    __syncthreads();
    if (tid < NE) {
        if (bcnt[tid]) atomicAdd(&counts[tid], bcnt[tid]);
        atomicAdd(&sum_probs[tid], bprob[tid]);
    }
}

// ---------------- exclusive scan over 8 experts ----------------
__global__ void scan_k(const int* __restrict__ counts, int* __restrict__ offsets) {
    if (threadIdx.x == 0) {
        int o = 0;
        for (int e = 0; e < NE; ++e) { offsets[e] = o; o += counts[e]; }
    }
}

// ---------------- scatter tokens into expert-grouped slots ----------------
__global__ __launch_bounds__(256) void scatter_k(
        const int* __restrict__ tk_idx, const int* __restrict__ offsets,
        int* __restrict__ cursor, int* __restrict__ slot_tok,
        int* __restrict__ inv_slot) {
    int t = blockIdx.x * 256 + threadIdx.x;
    if (t >= NTOK) return;
#pragma unroll
    for (int k = 0; k < 2; ++k) {
        int e = tk_idx[2 * t + k];
        int pos = atomicAdd(&cursor[e], 1);
        int s = offsets[e] + pos;
        slot_tok[s] = t;
        inv_slot[2 * t + k] = s;
    }
}

// ---------------- grouped MFMA GEMM: big tile, 16 waves, 2-phase dbuf ----------------
// BM x BN x BK64, 1024 threads = 16 waves (WMW x WNW), wave tile (BM/WMW)x(BN/WNW).
// 2-phase: stage(next tile) -> compute(cur) -> __syncthreads (drain). Per-tile work
// (~3000cy) >> load latency (~900cy) so the drain waits ~0 (the 128-tile rounds
// r2-r5 lacked exactly this margin). 8-slot XOR swizzle -> 2-way LDS reads (free).
// Dense grid: block -> (expert, m0) via 8-step scan of counts (no dead blocks).
template<int BM, int BN, int WMW, int WNW, int KD, bool GATHER, bool GELU>
__global__ __launch_bounds__(1024, 1) void gemm_big_k(
        const u16* __restrict__ A,      // GATHER: xb [NTOK][KD]; else hbuf [SLOTS_PAD][KD]
        const u16* __restrict__ Bt,     // [NE][ND][KD]
        const float* __restrict__ bias, // GELU: b1 [NE][ND]
        const int* __restrict__ counts, const int* __restrict__ offsets,
        const int* __restrict__ slot_tok,
        u16* __restrict__ outb, int ND) {
    constexpr int WTM = BM / WMW;          // 64
    constexpr int WTN = BN / WNW;          // 64 or 32
    constexpr int FM  = WTM / 16;          // 4
    constexpr int FN  = WTN / 16;          // 4 or 2
    constexpr int ABUF = BM * 64;          // u16 elems per A K-tile
    constexpr int BBUF = BN * 64;
    constexpr int BUFSZ = ABUF + BBUF;
    constexpr int AR  = BM / 128;          // staging rounds for A (2 or 1)
    constexpr int BR  = BN / 128;          // 2
    constexpr int NK  = KD / 64;

    // block -> (expert, m0) from counts (all blocks live)
    int mb = blockIdx.y;
    int e = -1, m0 = 0, accmb = 0;
    for (int ee = 0; ee < NE; ++ee) {
        int nb = (counts[ee] + BM - 1) / BM;
        if (e < 0 && mb < accmb + nb) { e = ee; m0 = (mb - accmb) * BM; }
        accmb += nb;
    }
    if (e < 0) return;
    int cnt  = counts[e];
    int base = offsets[e];
    int n0   = blockIdx.x * BN;

    __shared__ u16 smem[2 * BUFSZ];
    __shared__ int ids[BM];

    int tid  = threadIdx.x;
    int lane = tid & 63;
    int w    = tid >> 6;                   // 16 waves
    int wr   = w / WNW, wc = w % WNW;
    int lrow = lane & 15, khi = lane >> 4; // khi in 0..3

    if constexpr (GATHER) {
        for (int i = tid; i < BM; i += 1024)
            ids[i] = (m0 + i < cnt) ? slot_tok[base + m0 + i] : 0;
    }
    __syncthreads();

    const u16* Bte = Bt + (size_t)e * (size_t)ND * KD;
    int srow8 = tid >> 3;                  // 0..127 staging row within a round
    int sslot = tid & 7;                   // 16B slot within 128B row segment

    const u16* gA[AR];
#pragma unroll
    for (int a = 0; a < AR; ++a) {
        int r = a * 128 + srow8;
        size_t gr;
        if constexpr (GATHER) gr = (size_t)ids[r];
        else                  gr = (size_t)(base + m0 + r);
        gA[a] = A + gr * KD + ((sslot ^ (r & 7)) << 3);
    }
    const u16* gB[BR];
#pragma unroll
    for (int b = 0; b < BR; ++b) {
        int r = b * 128 + srow8;
        gB[b] = Bte + (size_t)(n0 + r) * KD + ((sslot ^ (r & 7)) << 3);
    }

    f32x4 acc[FM][FN];
#pragma unroll
    for (int m = 0; m < FM; ++m)
#pragma unroll
        for (int n = 0; n < FN; ++n) acc[m][n] = {0.f, 0.f, 0.f, 0.f};

    auto stage = [&](int buf, int t) {
        u16* d0 = smem + buf * BUFSZ;
#pragma unroll
        for (int a = 0; a < AR; ++a)
            gload_lds16(gA[a] + t * 64, d0 + a * 8192 + tid * 8);
#pragma unroll
        for (int b = 0; b < BR; ++b)
            gload_lds16(gB[b] + t * 64, d0 + ABUF + b * 8192 + tid * 8);
    };
    auto compute = [&](int buf) {
        const u16* As = smem + buf * BUFSZ;
        const u16* Bs = As + ABUF;
#pragma unroll
        for (int ks = 0; ks < 2; ++ks) {
            int slot = ks * 4 + khi;
            bf16x8 af[FM], bv[FN];
#pragma unroll
            for (int m = 0; m < FM; ++m) {
                int r = wr * WTM + m * 16 + lrow;
                af[m] = *reinterpret_cast<const bf16x8*>(
                    &As[r * 64 + ((slot ^ (r & 7)) << 3)]);
            }
#pragma unroll
            for (int n = 0; n < FN; ++n) {
                int r = wc * WTN + n * 16 + lrow;
                bv[n] = *reinterpret_cast<const bf16x8*>(
                    &Bs[r * 64 + ((slot ^ (r & 7)) << 3)]);
            }
            __builtin_amdgcn_s_setprio(1);
#pragma unroll
            for (int m = 0; m < FM; ++m)
#pragma unroll
                for (int n = 0; n < FN; ++n)
                    acc[m][n] = __builtin_amdgcn_mfma_f32_16x16x32_bf16(
                        af[m], bv[n], acc[m][n], 0, 0, 0);
            __builtin_amdgcn_s_setprio(0);
        }
    };

    stage(0, 0);
    __syncthreads();                       // buf0 ready
#pragma unroll 1
    for (int t = 0; t < NK; ++t) {
        if (t + 1 < NK) stage((t + 1) & 1, t + 1);  // issue next-tile loads first
        compute(t & 1);
        __syncthreads();                   // drain: next buf ready, cur reusable
    }

    // ---- epilogue: per-wave private 16-row LDS pack -> coalesced 16B stores ----
    constexpr int PST = WTN + 8;           // pack row stride (u16)
    u16* patch = smem + w * (16 * PST);
    float bvals[FN];
    if constexpr (GELU) {
#pragma unroll
        for (int n = 0; n < FN; ++n)
            bvals[n] = bias[(size_t)e * ND + n0 + wc * WTN + n * 16 + lrow];
    }
    constexpr int LPR = WTN / 8;           // lanes per packed row (8 or 4)
    constexpr int RPP = 64 / LPR;          // rows per read pass (8 or 16)
#pragma unroll
    for (int m = 0; m < FM; ++m) {
#pragma unroll
        for (int n = 0; n < FN; ++n)
#pragma unroll
            for (int i = 0; i < 4; ++i) {
                float v = acc[m][n][i];
                if constexpr (GELU) {
                    v += bvals[n];
                    v = 0.5f * v * (1.f + erff(v * 0.70710678118654752f));
                }
                patch[(khi * 4 + i) * PST + n * 16 + lrow] = f2bf(v);
            }
        __syncthreads();
#pragma unroll
        for (int p = 0; p < 16 / RPP; ++p) {
            int row = p * RPP + lane / LPR;           // 0..15
            int sl  = lane % LPR;
            uint4 q = *reinterpret_cast<const uint4*>(&patch[row * PST + sl * 8]);
            int grow = m0 + wr * WTM + m * 16 + row;
            if (grow < cnt)
                *reinterpret_cast<uint4*>(
                    outb + (size_t)(base + grow) * ND + n0 + wc * WTN + sl * 8) = q;
        }
        __syncthreads();
    }
}

// ---------------- combine: out[t] = sum_k w_k * (y[slot_k] + b2[e_k]) ----------------
__global__ __launch_bounds__(256) void combine_k(
        const int* __restrict__ tk_idx, const float* __restrict__ tk_w,
        const int* __restrict__ inv_slot, const u16* __restrict__ ybuf,
        const float* __restrict__ b2, float* __restrict__ out) {
    int gtid = blockIdx.x * 256 + threadIdx.x;
    int t = gtid >> 6;
    int lane = gtid & 63;
    int e0 = tk_idx[2 * t], e1 = tk_idx[2 * t + 1];
    float w0 = tk_w[2 * t], w1 = tk_w[2 * t + 1];
    int s0 = inv_slot[2 * t], s1 = inv_slot[2 * t + 1];

#pragma unroll
    for (int i = 0; i < 2; ++i) {
        int c = lane * 8 + i * 512;
        uint4 q0 = *reinterpret_cast<const uint4*>(ybuf + (size_t)s0 * HD + c);
        uint4 q1 = *reinterpret_cast<const uint4*>(ybuf + (size_t)s1 * HD + c);
        float y0[8] = {bf2f((u16)(q0.x&0xffff)), bf2f((u16)(q0.x>>16)),
                       bf2f((u16)(q0.y&0xffff)), bf2f((u16)(q0.y>>16)),
                       bf2f((u16)(q0.z&0xffff)), bf2f((u16)(q0.z>>16)),
                       bf2f((u16)(q0.w&0xffff)), bf2f((u16)(q0.w>>16))};
        float y1[8] = {bf2f((u16)(q1.x&0xffff)), bf2f((u16)(q1.x>>16)),
                       bf2f((u16)(q1.y&0xffff)), bf2f((u16)(q1.y>>16)),
                       bf2f((u16)(q1.z&0xffff)), bf2f((u16)(q1.z>>16)),
                       bf2f((u16)(q1.w&0xffff)), bf2f((u16)(q1.w>>16))};
        float r[8];
#pragma unroll
        for (int j = 0; j < 8; ++j) {
            float v0 = y0[j] + b2[e0 * HD + c + j];
            float v1 = y1[j] + b2[e1 * HD + c + j];
            r[j] = w0 * v0 + w1 * v1;
        }
        float* op = out + (size_t)t * HD + c;
        *reinterpret_cast<float4*>(op)     = make_float4(r[0], r[1], r[2], r[3]);
        *reinterpret_cast<float4*>(op + 4) = make_float4(r[4], r[5], r[6], r[7]);
    }
}

// ---------------- aux loss finalize ----------------
__global__ void finalize_k(const int* __restrict__ counts,
                           const float* __restrict__ sum_probs,
                           float* __restrict__ out_aux) {
    if (threadIdx.x == 0) {
        double s = 0.0;
        for (int e = 0; e < NE; ++e) s += (double)counts[e] * (double)sum_probs[e];
        out_aux[0] = (float)(s * (8.0 / (2.0 * (double)NTOK)));
    }
}

extern "C" void kernel_launch(void* const* d_in, const int* in_sizes, int n_in,
                              void* d_out, int out_size, void* d_ws, size_t ws_size,
                              hipStream_t stream) {
    const float* x   = (const float*)d_in[0];
    const float* gw  = (const float*)d_in[1];
    const float* W1  = (const float*)d_in[2];
    const float* b1  = (const float*)d_in[3];
    const float* W2  = (const float*)d_in[4];
    const float* b2  = (const float*)d_in[5];
    float* out = (float*)d_out;

    char* ws = (char*)d_ws;
    // meta block [0,512): counts@0, cursor@32, offsets@64, sum_probs@128
    int*   counts    = (int*)(ws + 0);
    int*   cursor    = (int*)(ws + 32);
    int*   offsets   = (int*)(ws + 64);
    float* sum_probs = (float*)(ws + 128);
    int*   tk_idx    = (int*)(ws + 512);                 // 32768 B
    float* tk_w      = (float*)(ws + 33280);             // 32768 B
    int*   slot_tok  = (int*)(ws + 66048);               // 32768 B
    int*   inv_slot  = (int*)(ws + 98816);               // 32768 B
    u16*   xb        = (u16*)(ws + 131584);              // 8,388,608 B
    u16*   W1t       = (u16*)(ws + 8520192);             // 33,554,432 B [ybuf aliases]
    u16*   W2t       = (u16*)(ws + 42074624);            // 33,554,432 B
    u16*   hbuf      = (u16*)(ws + 75629056);            // 34,078,720 B (SLOTS_PAD rows)
    u16*   ybuf      = W1t;                              // W1t dead after gemm1
    // total = 109,707,776 B

    hipMemsetAsync(ws, 0, 512, stream);

    cvtT_k<HD, DD><<<dim3(DD / 32, HD / 32, NE), 256, 0, stream>>>(W1, W1t);
    cvtT_k<DD, HD><<<dim3(HD / 32, DD / 32, NE), 256, 0, stream>>>(W2, W2t);
    router_k<<<NTOK / 4, 256, 0, stream>>>(x, gw, xb, counts, sum_probs, tk_idx, tk_w);
    scan_k<<<1, 64, 0, stream>>>(counts, offsets);
    scatter_k<<<NTOK / 256, 256, 0, stream>>>(tk_idx, offsets, cursor, slot_tok, inv_slot);

    // GEMM1: 256x256 tile, 16 waves 4x4; grid.y = max m-blocks (8192/256 + 8)
    gemm_big_k<256, 256, 4, 4, HD, true, true>
        <<<dim3(DD / 256, SLOTS / 256 + NE), 1024, 0, stream>>>(
        xb, W1t, b1, counts, offsets, slot_tok, hbuf, DD);
    // GEMM2: 128x256 tile, 16 waves 2x8; grid.y = 8192/128 + 8
    gemm_big_k<128, 256, 2, 8, DD, false, false>
        <<<dim3(HD / 256, SLOTS / 128 + NE), 1024, 0, stream>>>(
        hbuf, W2t, nullptr, counts, offsets, slot_tok, ybuf, HD);

    combine_k<<<NTOK / 4, 256, 0, stream>>>(tk_idx, tk_w, inv_slot, ybuf, b2, out);
    finalize_k<<<1, 64, 0, stream>>>(counts, sum_probs, out + (size_t)NTOK * HD);
}

// Round 7
// 220.880 us; speedup vs baseline: 1.3047x; 1.2481x over previous
//
#include <hip/hip_runtime.h>
#include <hip/hip_bf16.h>

#define NTOK 4096   // B*S
#define HD   1024   // hidden
#define DD   2048   // expert hidden
#define NE   8      // experts
#define SLOTS (2*NTOK)
#define SLOTS_PAD (SLOTS + 128)

typedef unsigned short u16;
typedef unsigned int   u32;
typedef __attribute__((ext_vector_type(8))) __bf16 bf16x8;
typedef __attribute__((ext_vector_type(4))) float  f32x4;

__device__ __forceinline__ float bf2f(u16 u) {
    u32 v = ((u32)u) << 16;
    return __uint_as_float(v);
}
__device__ __forceinline__ u16 f2bf(float f) {
    __hip_bfloat16 h = __float2bfloat16(f);   // RTN
    return *reinterpret_cast<u16*>(&h);
}

__device__ __forceinline__ void gload_lds16(const void* g, void* l) {
    __builtin_amdgcn_global_load_lds(
        (__attribute__((address_space(1))) void*)g,
        (__attribute__((address_space(3))) void*)l,
        16, 0, 0);
}

// ---------------- fused weight convert+transpose (W1 & W2 in one launch) -------
// src [e][R][C] f32 -> dst [e][C][R] bf16, 64x64 tiles, vectorized I/O.
__global__ __launch_bounds__(256) void cvt2_k(
        const float* __restrict__ W1, const float* __restrict__ W2,
        u16* __restrict__ W1t, u16* __restrict__ W2t) {
    int z = blockIdx.z;
    const float* src; u16* dst; int R, C;
    if (z < NE) { src = W1 + (size_t)z * HD * DD;        dst = W1t + (size_t)z * HD * DD;        R = HD; C = DD; }
    else        { src = W2 + (size_t)(z - NE) * DD * HD; dst = W2t + (size_t)(z - NE) * DD * HD; R = DD; C = HD; }
    int tcols = C >> 6;
    int r0 = (blockIdx.x / tcols) * 64;
    int c0 = (blockIdx.x % tcols) * 64;

    __shared__ u16 tile[64][68];
    int tid = threadIdx.x;
    int rr  = tid >> 4;            // 0..15
    int cc4 = (tid & 15) * 4;
#pragma unroll
    for (int j = 0; j < 4; ++j) {
        int r = rr + j * 16;
        float4 v = *reinterpret_cast<const float4*>(src + (size_t)(r0 + r) * C + c0 + cc4);
        tile[r][cc4 + 0] = f2bf(v.x); tile[r][cc4 + 1] = f2bf(v.y);
        tile[r][cc4 + 2] = f2bf(v.z); tile[r][cc4 + 3] = f2bf(v.w);
    }
    __syncthreads();
    int cc = tid >> 3, sl = tid & 7;
#pragma unroll
    for (int p = 0; p < 2; ++p) {
        int c = p * 32 + cc;
        u16 tmp[8];
#pragma unroll
        for (int k = 0; k < 8; ++k) tmp[k] = tile[sl * 8 + k][c];
        *reinterpret_cast<uint4*>(dst + (size_t)(c0 + c) * R + r0 + sl * 8) =
            *reinterpret_cast<uint4*>(tmp);
    }
}

// ---------------- router (fused x->bf16 convert): 1 wave per token ----------------
__global__ __launch_bounds__(256) void router_k(
        const float* __restrict__ x, const float* __restrict__ gw,
        u16* __restrict__ xb,
        int* __restrict__ counts, float* __restrict__ sum_probs,
        int* __restrict__ tk_idx, float* __restrict__ tk_w) {
    __shared__ int   bcnt[NE];
    __shared__ float bprob[NE];
    int tid = threadIdx.x;
    if (tid < NE) { bcnt[tid] = 0; bprob[tid] = 0.f; }
    __syncthreads();

    int gtid = blockIdx.x * 256 + tid;
    int t    = gtid >> 6;
    int lane = gtid & 63;

    float acc[NE] = {0.f,0.f,0.f,0.f,0.f,0.f,0.f,0.f};
    const float* xr = x + (size_t)t * HD;
    u16* xbr = xb + (size_t)t * HD;
#pragma unroll
    for (int i = 0; i < HD / 64; ++i) {
        int h = lane + i * 64;
        float xv = xr[h];
        xbr[h] = f2bf(xv);   // fused bf16 convert
        const float4* g = reinterpret_cast<const float4*>(gw + (size_t)h * NE);
        float4 g0 = g[0], g1 = g[1];
        acc[0] = fmaf(xv, g0.x, acc[0]); acc[1] = fmaf(xv, g0.y, acc[1]);
        acc[2] = fmaf(xv, g0.z, acc[2]); acc[3] = fmaf(xv, g0.w, acc[3]);
        acc[4] = fmaf(xv, g1.x, acc[4]); acc[5] = fmaf(xv, g1.y, acc[5]);
        acc[6] = fmaf(xv, g1.z, acc[6]); acc[7] = fmaf(xv, g1.w, acc[7]);
    }
#pragma unroll
    for (int off = 32; off >= 1; off >>= 1) {
#pragma unroll
        for (int e = 0; e < NE; ++e) acc[e] += __shfl_xor(acc[e], off);
    }
    float m = acc[0];
#pragma unroll
    for (int e = 1; e < NE; ++e) m = fmaxf(m, acc[e]);
    float p[NE]; float s = 0.f;
#pragma unroll
    for (int e = 0; e < NE; ++e) { p[e] = expf(acc[e] - m); s += p[e]; }
    float inv = 1.f / s;

    int i1 = 0; float v1 = p[0];
#pragma unroll
    for (int e = 1; e < NE; ++e) if (p[e] > v1) { v1 = p[e]; i1 = e; }
    int i2 = -1; float v2 = -1.f;
#pragma unroll
    for (int e = 0; e < NE; ++e) if (e != i1 && p[e] > v2) { v2 = p[e]; i2 = e; }
    float wsum = v1 + v2;

    if (lane < NE) atomicAdd(&bprob[lane], p[lane] * inv);
    if (lane == 0) {
        atomicAdd(&bcnt[i1], 1);
        atomicAdd(&bcnt[i2], 1);
        tk_idx[2 * t]     = i1;  tk_idx[2 * t + 1] = i2;
        tk_w[2 * t]       = v1 / wsum;
        tk_w[2 * t + 1]   = v2 / wsum;
    }
    __syncthreads();
    if (tid < NE) {
        if (bcnt[tid]) atomicAdd(&counts[tid], bcnt[tid]);
        atomicAdd(&sum_probs[tid], bprob[tid]);
    }
}

// ---------------- scatter (scan fused in): tokens -> expert-grouped slots --------
__global__ __launch_bounds__(256) void scatter_k(
        const int* __restrict__ tk_idx, const int* __restrict__ counts,
        int* __restrict__ cursor, int* __restrict__ slot_tok,
        int* __restrict__ inv_slot, int* __restrict__ offsets) {
    __shared__ int off[NE];
    if (threadIdx.x == 0) {
        int o = 0;
        for (int e = 0; e < NE; ++e) { off[e] = o; o += counts[e]; }
        if (blockIdx.x == 0)
            for (int e = 0; e < NE; ++e) offsets[e] = off[e];
    }
    __syncthreads();
    int t = blockIdx.x * 256 + threadIdx.x;
    if (t >= NTOK) return;
#pragma unroll
    for (int k = 0; k < 2; ++k) {
        int e = tk_idx[2 * t + k];
        int pos = atomicAdd(&cursor[e], 1);
        int s = off[e] + pos;
        slot_tok[s] = t;
        inv_slot[2 * t + k] = s;
    }
}

// ---------------- grouped MFMA GEMM: 128x128xBK64, 4 waves, single-buffer --------
// m97-class 2-barrier K-loop; the lever this round is CO-RESIDENCY: 33KB LDS +
// dense grid -> 3-4 live blocks/CU (12-16 waves) so inter-block overlap (m114)
// covers the barrier drains. 128B LDS rows + slot-XOR -> 2-way reads (free).
template<int KD, bool GATHER, bool GELU>
__global__ __launch_bounds__(256) void gemm_dense_k(
        const u16* __restrict__ A,      // GATHER: xb [NTOK][KD]; else hbuf [SLOTS_PAD][KD]
        const u16* __restrict__ Bt,     // [NE][ND][KD]
        const float* __restrict__ bias, // GELU: b1 [NE][ND]
        const int* __restrict__ counts, const int* __restrict__ offsets,
        const int* __restrict__ slot_tok,
        u16* __restrict__ outb, int ND) {
    // dense block mapping: blockIdx.y -> (expert, m0), no dead blocks (r6-proven)
    int mb = blockIdx.y;
    int e = -1, m0 = 0, accb = 0;
#pragma unroll
    for (int ee = 0; ee < NE; ++ee) {
        int nb = (counts[ee] + 127) >> 7;
        if (e < 0 && mb < accb + nb) { e = ee; m0 = (mb - accb) * 128; }
        accb += nb;
    }
    if (e < 0) return;
    int cnt = counts[e], base = offsets[e];
    int n0 = blockIdx.x * 128;

    __shared__ u16 As[128 * 64];   // 16 KB, rows of 128 B
    __shared__ u16 Bs[128 * 64];   // 16 KB
    __shared__ int ids[128];

    int tid  = threadIdx.x;
    int lane = tid & 63;
    int w    = tid >> 6;            // 4 waves, 2M x 2N
    int wr   = w >> 1, wc = w & 1;
    int lrow = lane & 15, khi = lane >> 4;

    if constexpr (GATHER) {
        if (tid < 128) ids[tid] = (m0 + tid < cnt) ? slot_tok[base + m0 + tid] : 0;
    }
    __syncthreads();

    const u16* Bte = Bt + (size_t)e * (size_t)ND * KD;
    int srow = tid >> 3;            // 0..31 (staging row within a 32-row round)
    int sslot = tid & 7;            // 16B slot in a 128B row

    const u16 *gA[4], *gB[4];       // 4 rounds x 32 rows = 128 rows
#pragma unroll
    for (int j = 0; j < 4; ++j) {
        int r = j * 32 + srow;
        size_t gr;
        if constexpr (GATHER) gr = (size_t)ids[r];
        else                  gr = (size_t)(base + m0 + r);
        gA[j] = A   + gr * KD                + ((sslot ^ (r & 7)) << 3);
        gB[j] = Bte + (size_t)(n0 + r) * KD  + ((sslot ^ (r & 7)) << 3);
    }

    f32x4 acc[4][4];
#pragma unroll
    for (int m = 0; m < 4; ++m)
#pragma unroll
        for (int n = 0; n < 4; ++n) acc[m][n] = {0.f, 0.f, 0.f, 0.f};

    constexpr int NK = KD / 64;
#pragma unroll 1
    for (int t = 0; t < NK; ++t) {
#pragma unroll
        for (int j = 0; j < 4; ++j) {
            gload_lds16(gA[j] + t * 64, (char*)As + j * 4096 + tid * 16);
            gload_lds16(gB[j] + t * 64, (char*)Bs + j * 4096 + tid * 16);
        }
        __syncthreads();            // tiles ready (vmcnt drained by sync)
#pragma unroll
        for (int ks = 0; ks < 2; ++ks) {
            int slot = ks * 4 + khi;
            bf16x8 af[4], bv[4];
#pragma unroll
            for (int m = 0; m < 4; ++m) {
                int r = wr * 64 + m * 16 + lrow;
                af[m] = *reinterpret_cast<const bf16x8*>(
                    &As[r * 64 + ((slot ^ (r & 7)) << 3)]);
            }
#pragma unroll
            for (int n = 0; n < 4; ++n) {
                int r = wc * 64 + n * 16 + lrow;
                bv[n] = *reinterpret_cast<const bf16x8*>(
                    &Bs[r * 64 + ((slot ^ (r & 7)) << 3)]);
            }
            __builtin_amdgcn_s_setprio(1);
#pragma unroll
            for (int m = 0; m < 4; ++m)
#pragma unroll
                for (int n = 0; n < 4; ++n)
                    acc[m][n] = __builtin_amdgcn_mfma_f32_16x16x32_bf16(
                        af[m], bv[n], acc[m][n], 0, 0, 0);
            __builtin_amdgcn_s_setprio(0);
        }
        __syncthreads();            // LDS reusable next iter
    }

    // ---- epilogue: per-wave 16-row LDS pack -> coalesced 16B stores ----
    constexpr int PST = 72;
    u16* patch = As + w * 16 * PST;   // 4 waves x 2304B, fits in As
    float bvals[4];
    if constexpr (GELU) {
#pragma unroll
        for (int n = 0; n < 4; ++n)
            bvals[n] = bias[(size_t)e * ND + n0 + wc * 64 + n * 16 + lrow];
    }
#pragma unroll
    for (int m = 0; m < 4; ++m) {
#pragma unroll
        for (int n = 0; n < 4; ++n)
#pragma unroll
            for (int i = 0; i < 4; ++i) {
                float v = acc[m][n][i];
                if constexpr (GELU) {
                    v += bvals[n];
                    v = 0.5f * v * (1.f + erff(v * 0.70710678118654752f));
                }
                patch[(khi * 4 + i) * PST + n * 16 + lrow] = f2bf(v);
            }
        __syncthreads();
        int prow = lane >> 3, sl = lane & 7;
#pragma unroll
        for (int p = 0; p < 2; ++p) {
            int row  = p * 8 + prow;
            uint4 q = *reinterpret_cast<const uint4*>(&patch[row * PST + sl * 8]);
            int grow = m0 + wr * 64 + m * 16 + row;
            if (grow < cnt)
                *reinterpret_cast<uint4*>(
                    outb + (size_t)(base + grow) * ND + n0 + wc * 64 + sl * 8) = q;
        }
        __syncthreads();
    }
}

// ---------------- combine: out[t] = sum_k w_k * (y[slot_k] + b2[e_k]) ----------------
__global__ __launch_bounds__(256) void combine_k(
        const int* __restrict__ tk_idx, const float* __restrict__ tk_w,
        const int* __restrict__ inv_slot, const u16* __restrict__ ybuf,
        const float* __restrict__ b2, float* __restrict__ out) {
    int gtid = blockIdx.x * 256 + threadIdx.x;
    int t = gtid >> 6;
    int lane = gtid & 63;
    int e0 = tk_idx[2 * t], e1 = tk_idx[2 * t + 1];
    float w0 = tk_w[2 * t], w1 = tk_w[2 * t + 1];
    int s0 = inv_slot[2 * t], s1 = inv_slot[2 * t + 1];

#pragma unroll
    for (int i = 0; i < 2; ++i) {
        int c = lane * 8 + i * 512;
        uint4 q0 = *reinterpret_cast<const uint4*>(ybuf + (size_t)s0 * HD + c);
        uint4 q1 = *reinterpret_cast<const uint4*>(ybuf + (size_t)s1 * HD + c);
        float y0[8] = {bf2f((u16)(q0.x&0xffff)), bf2f((u16)(q0.x>>16)),
                       bf2f((u16)(q0.y&0xffff)), bf2f((u16)(q0.y>>16)),
                       bf2f((u16)(q0.z&0xffff)), bf2f((u16)(q0.z>>16)),
                       bf2f((u16)(q0.w&0xffff)), bf2f((u16)(q0.w>>16))};
        float y1[8] = {bf2f((u16)(q1.x&0xffff)), bf2f((u16)(q1.x>>16)),
                       bf2f((u16)(q1.y&0xffff)), bf2f((u16)(q1.y>>16)),
                       bf2f((u16)(q1.z&0xffff)), bf2f((u16)(q1.z>>16)),
                       bf2f((u16)(q1.w&0xffff)), bf2f((u16)(q1.w>>16))};
        float r[8];
#pragma unroll
        for (int j = 0; j < 8; ++j) {
            float v0 = y0[j] + b2[e0 * HD + c + j];
            float v1 = y1[j] + b2[e1 * HD + c + j];
            r[j] = w0 * v0 + w1 * v1;
        }
        float* op = out + (size_t)t * HD + c;
        *reinterpret_cast<float4*>(op)     = make_float4(r[0], r[1], r[2], r[3]);
        *reinterpret_cast<float4*>(op + 4) = make_float4(r[4], r[5], r[6], r[7]);
    }
}

// ---------------- aux loss finalize ----------------
__global__ void finalize_k(const int* __restrict__ counts,
                           const float* __restrict__ sum_probs,
                           float* __restrict__ out_aux) {
    if (threadIdx.x == 0) {
        double s = 0.0;
        for (int e = 0; e < NE; ++e) s += (double)counts[e] * (double)sum_probs[e];
        out_aux[0] = (float)(s * (8.0 / (2.0 * (double)NTOK)));
    }
}

extern "C" void kernel_launch(void* const* d_in, const int* in_sizes, int n_in,
                              void* d_out, int out_size, void* d_ws, size_t ws_size,
                              hipStream_t stream) {
    const float* x   = (const float*)d_in[0];
    const float* gw  = (const float*)d_in[1];
    const float* W1  = (const float*)d_in[2];
    const float* b1  = (const float*)d_in[3];
    const float* W2  = (const float*)d_in[4];
    const float* b2  = (const float*)d_in[5];
    float* out = (float*)d_out;

    char* ws = (char*)d_ws;
    // meta block [0,512): counts@0, cursor@32, offsets@64, sum_probs@128
    int*   counts    = (int*)(ws + 0);
    int*   cursor    = (int*)(ws + 32);
    int*   offsets   = (int*)(ws + 64);
    float* sum_probs = (float*)(ws + 128);
    int*   tk_idx    = (int*)(ws + 512);                 // 32768 B
    float* tk_w      = (float*)(ws + 33280);             // 32768 B
    int*   slot_tok  = (int*)(ws + 66048);               // 32768 B
    int*   inv_slot  = (int*)(ws + 98816);               // 32768 B
    u16*   xb        = (u16*)(ws + 131584);              // 8,388,608 B
    u16*   W1t       = (u16*)(ws + 8520192);             // 33,554,432 B [ybuf aliases]
    u16*   W2t       = (u16*)(ws + 42074624);            // 33,554,432 B
    u16*   hbuf      = (u16*)(ws + 75629056);            // 34,078,720 B (SLOTS_PAD rows)
    u16*   ybuf      = W1t;                              // W1t dead after gemm1
    // total = 109,707,776 B

    hipMemsetAsync(ws, 0, 512, stream);

    cvt2_k<<<dim3(512, 1, 2 * NE), 256, 0, stream>>>(W1, W2, W1t, W2t);
    router_k<<<NTOK / 4, 256, 0, stream>>>(x, gw, xb, counts, sum_probs, tk_idx, tk_w);
    scatter_k<<<NTOK / 256, 256, 0, stream>>>(tk_idx, counts, cursor,
                                              slot_tok, inv_slot, offsets);

    // dense grids: grid.y = max total m-blocks = 8192/128 + (NE-1 partials) <= 72
    gemm_dense_k<HD, true, true><<<dim3(DD / 128, 72, 1), 256, 0, stream>>>(
        xb, W1t, b1, counts, offsets, slot_tok, hbuf, DD);
    gemm_dense_k<DD, false, false><<<dim3(HD / 128, 72, 1), 256, 0, stream>>>(
        hbuf, W2t, nullptr, counts, offsets, slot_tok, ybuf, HD);

    combine_k<<<NTOK / 4, 256, 0, stream>>>(tk_idx, tk_w, inv_slot, ybuf, b2, out);
    finalize_k<<<1, 64, 0, stream>>>(counts, sum_probs, out + (size_t)NTOK * HD);
}